// Round 8
// baseline (173.945 us; speedup 1.0000x reference)
//
#include <hip/hip_runtime.h>
#include <hip/hip_cooperative_groups.h>
#include <math.h>

namespace cg = cooperative_groups;

// Problem constants (CapsNet routing)
#define BB   256   // batch
#define NI   1152  // input capsules
#define DI   8     // input dim
#define NJ   10    // output capsules
#define DJ   16    // output dim
#define NCHUNK 18  // NI / CHUNK
#define CHUNK  64  // i per block
#define BG     32  // batch per block
#define NBG    8   // BB / BG
#define GRID_MAIN (NJ * NCHUNK * NBG)   // 1440 = 8 XCD x 180

// DPP cross-lane adds (VALU pipe, no LDS traffic)
// 0x124 row_ror:4, 0x128 row_ror:8 (16-lane row); 0x0B1 quad lane^1, 0x04E quad lane^2
template <int CTRL>
__device__ __forceinline__ float dpp_add(float x) {
    int xi = __float_as_int(x);
    int yi = __builtin_amdgcn_update_dpp(0, xi, CTRL, 0xF, 0xF, true);
    return x + __int_as_float(yi);
}

__device__ __forceinline__ float dot8(const float4* Wq, int q, float4 u0, float4 u1) {
    return Wq[2*q].x * u0.x + Wq[2*q].y * u0.y + Wq[2*q].z * u0.z + Wq[2*q].w * u0.w +
           Wq[2*q+1].x * u1.x + Wq[2*q+1].y * u1.y + Wq[2*q+1].z * u1.z + Wq[2*q+1].w * u1.w;
}

#define LDS_FLOATS (16 * 17 * 16)   // 17408 B; phase A tile / aliased by BV (2560 f)

struct Ctx {
    int j, chunk, bg, i0, b0, tid, il, dq, lane, w, g, xcd, local;
};

// XCD-bijective swizzle: xcd = bid&7 owns local 0..179 -> bg == xcd, all (j,chunk).
// All of spart/delta/c for batch-group bg is produced AND consumed on XCD bg.
__device__ __forceinline__ Ctx make_ctx(int bid, int tid) {
    Ctx c;
    c.xcd = bid & 7; c.local = bid >> 3;
    int gx = c.xcd * (GRID_MAIN / 8) + c.local;
    c.j = gx % NJ; int r = gx / NJ;
    c.chunk = r % NCHUNK; c.bg = r / NCHUNK;   // bg == xcd by construction
    c.i0 = c.chunk * CHUNK; c.b0 = c.bg * BG;
    c.tid = tid; c.il = tid >> 2; c.dq = tid & 3;
    c.lane = tid & 63; c.w = tid >> 6; c.g = (c.lane >> 4) & 3;
    return c;
}

__device__ __forceinline__ void loadW(const float* __restrict__ W, const Ctx& cx, float4* Wq) {
    const float4* wp = (const float4*)(W +
        (((size_t)cx.j * NI + cx.i0 + cx.il) * DJ + cx.dq * 4) * DI);
#pragma unroll
    for (int q = 0; q < 8; ++q) Wq[q] = wp[q];
}

// ---- phase A: spart[ch][b][j][d] = sum_{i in chunk} c*uhat ----
template <bool USE_C>
__device__ __forceinline__ void phaseA_body(const Ctx& cx, const float* __restrict__ u,
                                            const float* __restrict__ c,
                                            float* __restrict__ spart,
                                            const float4* Wq, float* lds) {
    for (int half = 0; half < 2; ++half) {
        int bbase = cx.b0 + half * 16;
#pragma unroll 4
        for (int s = 0; s < 16; ++s) {
            int b = bbase + s;
            const float4* up = (const float4*)(u + ((size_t)b * NI + cx.i0 + cx.il) * DI);
            float4 u0 = up[0], u1 = up[1];
            float ci = USE_C ? c[((size_t)b * NJ + cx.j) * NI + cx.i0 + cx.il]
                             : 0.1f;   // softmax of zeros over NJ=10
            float p[4];
#pragma unroll
            for (int q = 0; q < 4; ++q) p[q] = ci * dot8(Wq, q, u0, u1);
#pragma unroll
            for (int q = 0; q < 4; ++q) p[q] = dpp_add<0x124>(p[q]);
#pragma unroll
            for (int q = 0; q < 4; ++q) p[q] = dpp_add<0x128>(p[q]);
            if ((cx.lane & 12) == 0) {
                float4 v4; v4.x = p[0]; v4.y = p[1]; v4.z = p[2]; v4.w = p[3];
                *(float4*)&lds[((s * 17) + (cx.w * 4 + cx.g)) * 16 + cx.dq * 4] = v4;
            }
        }
        __syncthreads();
        {
            int bb16 = cx.tid >> 4, dd = cx.tid & 15;
            float s2 = 0.f;
#pragma unroll
            for (int gg = 0; gg < 16; ++gg) s2 += lds[((bb16 * 17) + gg) * 16 + dd];
            spart[(((size_t)cx.chunk * BB + bbase + bb16) * NJ + cx.j) * DJ + dd] = s2;
        }
        __syncthreads();
    }
}

// ---- phase BV: v = squash(sum_ch spart) in LDS, then delta (+)= v . uhat ----
__device__ __forceinline__ void phaseBV_body(const Ctx& cx, const float* __restrict__ u,
                                             const float* __restrict__ spart,
                                             float* __restrict__ delta,
                                             const float4* Wq, float* lds, bool accum) {
    float* vsm  = lds;             // [32][16]
    float* bres = lds + BG * DJ;   // [32][64]
    {
        int bb2 = cx.tid >> 4, dd = cx.tid & 15;
#pragma unroll
        for (int h = 0; h < 2; ++h) {
            int bb = bb2 + 16 * h;
            int b = cx.b0 + bb;
            float s = 0.f;
#pragma unroll
            for (int ch = 0; ch < NCHUNK; ++ch)
                s += spart[(((size_t)ch * BB + b) * NJ + cx.j) * DJ + dd];
            float sq = s * s;
            sq = dpp_add<0x0B1>(sq);
            sq = dpp_add<0x04E>(sq);
            sq = dpp_add<0x124>(sq);
            sq = dpp_add<0x128>(sq);
            float scale = (sq / (1.f + sq)) / sqrtf(sq + 1e-7f);
            vsm[bb * DJ + dd] = s * scale;
        }
    }
    __syncthreads();
#pragma unroll 4
    for (int bb = 0; bb < BG; ++bb) {
        int b = cx.b0 + bb;
        const float4* up = (const float4*)(u + ((size_t)b * NI + cx.i0 + cx.il) * DI);
        float4 u0 = up[0], u1 = up[1];
        float4 vv = *(const float4*)&vsm[bb * DJ + cx.dq * 4];
        float p = 0.f;
#pragma unroll
        for (int q = 0; q < 4; ++q) {
            float vd = (q == 0) ? vv.x : (q == 1) ? vv.y : (q == 2) ? vv.z : vv.w;
            p += vd * dot8(Wq, q, u0, u1);
        }
        p = dpp_add<0x0B1>(p);
        p = dpp_add<0x04E>(p);
        if (cx.dq == 0) bres[bb * CHUNK + cx.il] = p;
    }
    __syncthreads();
#pragma unroll
    for (int h = 0; h < 2; ++h) {
        int bb = (cx.tid >> 4) + 16 * h;
        int q  = cx.tid & 15;
        float4 val = ((const float4*)(bres + bb * CHUNK))[q];
        float* dst = delta + (((size_t)(cx.b0 + bb) * NJ + cx.j) * NI + cx.i0) + q * 4;
        if (accum) {
            float4 old = *(const float4*)dst;
            val.x += old.x; val.y += old.y; val.z += old.z; val.w += old.w;
        }
        *(float4*)dst = val;
    }
    __syncthreads();
}

// ---- phase SM: c = softmax_j(delta), XCD-local (b range = xcd's bg) ----
__device__ __forceinline__ void phaseSM_body(const Ctx& cx, const float* __restrict__ delta,
                                             float* __restrict__ c) {
    int idx_local = cx.local * 256 + cx.tid;
    if (idx_local < BG * NI) {                 // 36864 items per XCD
        int b = cx.xcd * BG + idx_local / NI;
        int i = idx_local % NI;
        float x[NJ];
        float mx = -1e30f;
#pragma unroll
        for (int jj = 0; jj < NJ; ++jj) {
            x[jj] = delta[((size_t)b * NJ + jj) * NI + i];
            mx = fmaxf(mx, x[jj]);
        }
        float ssum = 0.f;
#pragma unroll
        for (int jj = 0; jj < NJ; ++jj) { x[jj] = __expf(x[jj] - mx); ssum += x[jj]; }
        float rs = 1.f / ssum;
#pragma unroll
        for (int jj = 0; jj < NJ; ++jj)
            c[((size_t)b * NJ + jj) * NI + i] = x[jj] * rs;
    }
}

// ---- phase V: out = squash(sum_ch spart), XCD-local ----
__device__ __forceinline__ void phaseV_body(const Ctx& cx, const float* __restrict__ spart,
                                            float* __restrict__ out) {
    int idx_local = cx.local * 256 + cx.tid;
    if (idx_local < BG * NJ * DJ) {            // 5120 items per XCD
        int gidx = cx.xcd * (BG * NJ * DJ) + idx_local;   // = (b*NJ+j)*DJ+d
        float s = 0.f;
#pragma unroll
        for (int ch = 0; ch < NCHUNK; ++ch)
            s += spart[(size_t)ch * (BB * NJ * DJ) + gidx];
        float sq = s * s;
        sq = dpp_add<0x0B1>(sq);
        sq = dpp_add<0x04E>(sq);
        sq = dpp_add<0x124>(sq);
        sq = dpp_add<0x128>(sq);
        float scale = (sq / (1.f + sq)) / sqrtf(sq + 1e-7f);
        out[gidx] = s * scale;
    }
}

// =================== cooperative single-kernel path ===================
__global__ __launch_bounds__(256, 6) void caps_coop(
    const float* __restrict__ u, const float* __restrict__ W,
    float* __restrict__ out, float* __restrict__ delta,
    float* __restrict__ c, float* __restrict__ spart)
{
    cg::grid_group grid = cg::this_grid();
    __shared__ __align__(16) float lds[LDS_FLOATS];
    Ctx cx = make_ctx(blockIdx.x, threadIdx.x);
    float4 Wq[8];
    loadW(W, cx, Wq);

    phaseA_body<false>(cx, u, c, spart, Wq, lds);
    __threadfence(); grid.sync(); __threadfence();
    phaseBV_body(cx, u, spart, delta, Wq, lds, false);
    __threadfence(); grid.sync(); __threadfence();
    phaseSM_body(cx, delta, c);
    __threadfence(); grid.sync(); __threadfence();
    phaseA_body<true>(cx, u, c, spart, Wq, lds);
    __threadfence(); grid.sync(); __threadfence();
    phaseBV_body(cx, u, spart, delta, Wq, lds, true);
    __threadfence(); grid.sync(); __threadfence();
    phaseSM_body(cx, delta, c);
    __threadfence(); grid.sync(); __threadfence();
    phaseA_body<true>(cx, u, c, spart, Wq, lds);
    __threadfence(); grid.sync(); __threadfence();
    phaseV_body(cx, spart, out);
}

// =================== fallback multi-kernel path (8 launches) ===================
template <bool USE_C>
__global__ __launch_bounds__(256) void k_sA(const float* __restrict__ u,
                                            const float* __restrict__ W,
                                            const float* __restrict__ c,
                                            float* __restrict__ spart) {
    __shared__ __align__(16) float lds[LDS_FLOATS];
    Ctx cx = make_ctx(blockIdx.x, threadIdx.x);
    float4 Wq[8];
    loadW(W, cx, Wq);
    phaseA_body<USE_C>(cx, u, c, spart, Wq, lds);
}

__global__ __launch_bounds__(256) void k_sBV(const float* __restrict__ u,
                                             const float* __restrict__ W,
                                             const float* __restrict__ spart,
                                             float* __restrict__ delta, int accum) {
    __shared__ __align__(16) float lds[LDS_FLOATS];
    Ctx cx = make_ctx(blockIdx.x, threadIdx.x);
    float4 Wq[8];
    loadW(W, cx, Wq);
    phaseBV_body(cx, u, spart, delta, Wq, lds, accum != 0);
}

__global__ __launch_bounds__(256) void k_SM(const float* __restrict__ delta,
                                            float* __restrict__ c) {
    Ctx cx = make_ctx(blockIdx.x, threadIdx.x);
    phaseSM_body(cx, delta, c);
}

__global__ __launch_bounds__(256) void k_V(const float* __restrict__ spart,
                                           float* __restrict__ out) {
    Ctx cx = make_ctx(blockIdx.x, threadIdx.x);
    phaseV_body(cx, spart, out);
}

extern "C" void kernel_launch(void* const* d_in, const int* in_sizes, int n_in,
                              void* d_out, int out_size, void* d_ws, size_t ws_size,
                              hipStream_t stream) {
    const float* u = (const float*)d_in[0];   // (256,1152,8)
    const float* W = (const float*)d_in[1];   // (10,1152,16,8)
    float* out = (float*)d_out;               // (256,10,16)
    float* ws  = (float*)d_ws;

    float* delta = ws;                                      // BB*NJ*NI  [b][j][i]
    float* c     = delta + (size_t)BB * NJ * NI;            // BB*NJ*NI  [b][j][i]
    float* spart = c     + (size_t)BB * NJ * NI;            // NCHUNK*BB*NJ*DJ

    // Preflight (host-side queries only; capture-safe, deterministic)
    int dev = 0; (void)hipGetDevice(&dev);
    int coop = 0; (void)hipDeviceGetAttribute(&coop, hipDeviceAttributeCooperativeLaunch, dev);
    int nCU = 0;  (void)hipDeviceGetAttribute(&nCU, hipDeviceAttributeMultiprocessorCount, dev);
    int maxActive = 0;
    (void)hipOccupancyMaxActiveBlocksPerMultiprocessor(&maxActive, (const void*)caps_coop, 256, 0);
    bool use_coop = (coop != 0) && ((long)maxActive * (long)nCU >= GRID_MAIN);

    if (use_coop) {
        void* args[] = { (void*)&u, (void*)&W, (void*)&out,
                         (void*)&delta, (void*)&c, (void*)&spart };
        hipError_t e = hipLaunchCooperativeKernel((const void*)caps_coop,
                                                  dim3(GRID_MAIN), dim3(256), args, 0, stream);
        if (e == hipSuccess) return;
    }

    // Fallback: proven round-5 kernels + k_v fused into k_b (BG=32), 8 launches
    dim3 blk(256);
    k_sA<false><<<GRID_MAIN, blk, 0, stream>>>(u, W, c, spart);
    k_sBV<<<GRID_MAIN, blk, 0, stream>>>(u, W, spart, delta, 0);
    k_SM<<<GRID_MAIN, blk, 0, stream>>>(delta, c);
    k_sA<true><<<GRID_MAIN, blk, 0, stream>>>(u, W, c, spart);
    k_sBV<<<GRID_MAIN, blk, 0, stream>>>(u, W, spart, delta, 1);
    k_SM<<<GRID_MAIN, blk, 0, stream>>>(delta, c);
    k_sA<true><<<GRID_MAIN, blk, 0, stream>>>(u, W, c, spart);
    k_V<<<GRID_MAIN, blk, 0, stream>>>(spart, out);
}

// Round 9
// 161.863 us; speedup vs baseline: 1.0746x; 1.0746x over previous
//
#include <hip/hip_runtime.h>
#include <math.h>

// Problem constants (CapsNet routing)
#define BB   256   // batch
#define NI   1152  // input capsules
#define DI   8     // input dim
#define NJ   10    // output capsules
#define DJ   16    // output dim
#define NCHUNK 18  // NI / CHUNK
#define CHUNK  64  // i per block
#define BG     32  // batch per block
#define NBG    8   // BB / BG
#define GRID_MAIN (NJ * NCHUNK * NBG)   // 1440 = 8 XCD x 180

// DPP cross-lane adds (VALU pipe, no LDS traffic)
// 0x124 row_ror:4, 0x128 row_ror:8 (16-lane row); 0x0B1 quad lane^1, 0x04E quad lane^2
template <int CTRL>
__device__ __forceinline__ float dpp_add(float x) {
    int xi = __float_as_int(x);
    int yi = __builtin_amdgcn_update_dpp(0, xi, CTRL, 0xF, 0xF, true);
    return x + __int_as_float(yi);
}

__device__ __forceinline__ float dot8(const float4* Wq, int q, float4 u0, float4 u1) {
    return Wq[2*q].x * u0.x + Wq[2*q].y * u0.y + Wq[2*q].z * u0.z + Wq[2*q].w * u0.w +
           Wq[2*q+1].x * u1.x + Wq[2*q+1].y * u1.y + Wq[2*q+1].z * u1.z + Wq[2*q+1].w * u1.w;
}

struct Ctx {
    int j, chunk, bg, i0, b0, tid, il, dq, lane, w, g, xcd, local;
};

// XCD-bijective swizzle: xcd = bid&7 owns local 0..179 -> bg == xcd, all (j,chunk).
// All of spart/delta for batch-group bg is produced AND consumed on XCD bg.
__device__ __forceinline__ Ctx make_ctx(int bid, int tid) {
    Ctx c;
    c.xcd = bid & 7; c.local = bid >> 3;
    int gx = c.xcd * (GRID_MAIN / 8) + c.local;
    c.j = gx % NJ; int r = gx / NJ;
    c.chunk = r % NCHUNK; c.bg = r / NCHUNK;   // bg == xcd by construction
    c.i0 = c.chunk * CHUNK; c.b0 = c.bg * BG;
    c.tid = tid; c.il = tid >> 2; c.dq = tid & 3;
    c.lane = tid & 63; c.w = tid >> 6; c.g = (c.lane >> 4) & 3;
    return c;
}

__device__ __forceinline__ void loadW(const float* __restrict__ W, const Ctx& cx, float4* Wq) {
    const float4* wp = (const float4*)(W +
        (((size_t)cx.j * NI + cx.i0 + cx.il) * DJ + cx.dq * 4) * DI);
#pragma unroll
    for (int q = 0; q < 8; ++q) Wq[q] = wp[q];
}

// ---- phase A core: spart[ch][b][j][d] = sum_{i in chunk} c*uhat ----
// CSRC: 0 = ci = 0.1 (iter 0), 1 = ci from LDS ctile (softmax fused in prologue)
template <int CSRC>
__device__ __forceinline__ void phaseA_body(const Ctx& cx, const float* __restrict__ u,
                                            const float* __restrict__ ctile,
                                            float* __restrict__ spart,
                                            const float4* Wq, float* sres) {
    for (int half = 0; half < 2; ++half) {
        int bbase = cx.b0 + half * 16;
#pragma unroll 4
        for (int s = 0; s < 16; ++s) {
            int b = bbase + s;
            const float4* up = (const float4*)(u + ((size_t)b * NI + cx.i0 + cx.il) * DI);
            float4 u0 = up[0], u1 = up[1];
            float ci = (CSRC == 1) ? ctile[(half * 16 + s) * CHUNK + cx.il]
                                   : 0.1f;   // softmax of zeros over NJ=10
            float p[4];
#pragma unroll
            for (int q = 0; q < 4; ++q) p[q] = ci * dot8(Wq, q, u0, u1);
#pragma unroll
            for (int q = 0; q < 4; ++q) p[q] = dpp_add<0x124>(p[q]);
#pragma unroll
            for (int q = 0; q < 4; ++q) p[q] = dpp_add<0x128>(p[q]);
            if ((cx.lane & 12) == 0) {
                float4 v4; v4.x = p[0]; v4.y = p[1]; v4.z = p[2]; v4.w = p[3];
                *(float4*)&sres[((s * 17) + (cx.w * 4 + cx.g)) * 16 + cx.dq * 4] = v4;
            }
        }
        __syncthreads();
        {
            int bb16 = cx.tid >> 4, dd = cx.tid & 15;
            float s2 = 0.f;
#pragma unroll
            for (int gg = 0; gg < 16; ++gg) s2 += sres[((bb16 * 17) + gg) * 16 + dd];
            spart[(((size_t)cx.chunk * BB + bbase + bb16) * NJ + cx.j) * DJ + dd] = s2;
        }
        __syncthreads();
    }
}

// ---- k_A0: iteration 0 (c = 0.1 analytic) ----
__global__ __launch_bounds__(256) void k_A0(const float* __restrict__ u,
                                            const float* __restrict__ W,
                                            float* __restrict__ spart) {
    __shared__ __align__(16) float sres[16 * 17 * 16];   // 17408 B
    Ctx cx = make_ctx(blockIdx.x, threadIdx.x);
    float4 Wq[8];
    loadW(W, cx, Wq);
    phaseA_body<0>(cx, u, nullptr, spart, Wq, sres);
}

// ---- k_Af: softmax fused. Prologue: ctile[b'][i'] = softmax_j(delta[b,:,i])[j]
// for this block's j, computed from delta (XCD-local L2). Then phase A. ----
__global__ __launch_bounds__(256) void k_Af(const float* __restrict__ u,
                                            const float* __restrict__ W,
                                            const float* __restrict__ delta,
                                            float* __restrict__ spart) {
    __shared__ __align__(16) float sres[16 * 17 * 16];   // 17408 B
    __shared__ __align__(16) float ctile[BG * CHUNK];    // 8192 B
    Ctx cx = make_ctx(blockIdx.x, threadIdx.x);
    float4 Wq[8];
    loadW(W, cx, Wq);

    // softmax prologue: 2048 (b',i') pairs, 8 per thread, coalesced over i'
#pragma unroll
    for (int p = 0; p < 8; ++p) {
        int idx = p * 256 + cx.tid;        // 0..2047
        int bb = idx >> 6;                 // 0..31
        int ii = idx & 63;                 // 0..63
        int b = cx.b0 + bb;
        const float* dp = delta + (size_t)b * NJ * NI + cx.i0 + ii;
        float x[NJ];
        float mx = -1e30f;
#pragma unroll
        for (int jj = 0; jj < NJ; ++jj) {
            x[jj] = dp[(size_t)jj * NI];
            mx = fmaxf(mx, x[jj]);
        }
        float ssum = 0.f;
#pragma unroll
        for (int jj = 0; jj < NJ; ++jj) { x[jj] = __expf(x[jj] - mx); ssum += x[jj]; }
        ctile[bb * CHUNK + ii] = x[cx.j] / ssum;
    }
    __syncthreads();

    phaseA_body<1>(cx, u, ctile, spart, Wq, sres);
}

// ---- k_BV: v = squash(sum_ch spart) in LDS, then delta (+)= v . uhat ----
__global__ __launch_bounds__(256) void k_BV(const float* __restrict__ u,
                                            const float* __restrict__ W,
                                            const float* __restrict__ spart,
                                            float* __restrict__ delta, int accum) {
    __shared__ __align__(16) float vsm[BG * DJ];       // 2 KB
    __shared__ __align__(16) float bres[BG * CHUNK];   // 8 KB
    Ctx cx = make_ctx(blockIdx.x, threadIdx.x);
    float4 Wq[8];
    loadW(W, cx, Wq);

    {
        int bb2 = cx.tid >> 4, dd = cx.tid & 15;
#pragma unroll
        for (int h = 0; h < 2; ++h) {
            int bb = bb2 + 16 * h;
            int b = cx.b0 + bb;
            float s = 0.f;
#pragma unroll
            for (int ch = 0; ch < NCHUNK; ++ch)
                s += spart[(((size_t)ch * BB + b) * NJ + cx.j) * DJ + dd];
            float sq = s * s;
            sq = dpp_add<0x0B1>(sq);
            sq = dpp_add<0x04E>(sq);
            sq = dpp_add<0x124>(sq);
            sq = dpp_add<0x128>(sq);
            float scale = (sq / (1.f + sq)) / sqrtf(sq + 1e-7f);
            vsm[bb * DJ + dd] = s * scale;
        }
    }
    __syncthreads();
#pragma unroll 4
    for (int bb = 0; bb < BG; ++bb) {
        int b = cx.b0 + bb;
        const float4* up = (const float4*)(u + ((size_t)b * NI + cx.i0 + cx.il) * DI);
        float4 u0 = up[0], u1 = up[1];
        float4 vv = *(const float4*)&vsm[bb * DJ + cx.dq * 4];
        float p = 0.f;
#pragma unroll
        for (int q = 0; q < 4; ++q) {
            float vd = (q == 0) ? vv.x : (q == 1) ? vv.y : (q == 2) ? vv.z : vv.w;
            p += vd * dot8(Wq, q, u0, u1);
        }
        p = dpp_add<0x0B1>(p);
        p = dpp_add<0x04E>(p);
        if (cx.dq == 0) bres[bb * CHUNK + cx.il] = p;
    }
    __syncthreads();
#pragma unroll
    for (int h = 0; h < 2; ++h) {
        int bb = (cx.tid >> 4) + 16 * h;
        int q  = cx.tid & 15;
        float4 val = ((const float4*)(bres + bb * CHUNK))[q];
        float* dst = delta + (((size_t)(cx.b0 + bb) * NJ + cx.j) * NI + cx.i0) + q * 4;
        if (accum) {
            float4 old = *(const float4*)dst;
            val.x += old.x; val.y += old.y; val.z += old.z; val.w += old.w;
        }
        *(float4*)dst = val;
    }
}

// ---- k_V: out = squash(sum_ch spart), XCD-local indexing ----
__global__ __launch_bounds__(256) void k_V(const float* __restrict__ spart,
                                           float* __restrict__ out) {
    Ctx cx = make_ctx(blockIdx.x, threadIdx.x);
    int idx_local = cx.local * 256 + cx.tid;
    if (idx_local < BG * NJ * DJ) {            // 5120 items per XCD
        int gidx = cx.xcd * (BG * NJ * DJ) + idx_local;   // = (b*NJ+j)*DJ+d
        float s = 0.f;
#pragma unroll
        for (int ch = 0; ch < NCHUNK; ++ch)
            s += spart[(size_t)ch * (BB * NJ * DJ) + gidx];
        float sq = s * s;
        sq = dpp_add<0x0B1>(sq);
        sq = dpp_add<0x04E>(sq);
        sq = dpp_add<0x124>(sq);
        sq = dpp_add<0x128>(sq);
        float scale = (sq / (1.f + sq)) / sqrtf(sq + 1e-7f);
        out[gidx] = s * scale;
    }
}

extern "C" void kernel_launch(void* const* d_in, const int* in_sizes, int n_in,
                              void* d_out, int out_size, void* d_ws, size_t ws_size,
                              hipStream_t stream) {
    const float* u = (const float*)d_in[0];   // (256,1152,8)
    const float* W = (const float*)d_in[1];   // (10,1152,16,8)
    float* out = (float*)d_out;               // (256,10,16)
    float* ws  = (float*)d_ws;

    float* delta = ws;                                      // BB*NJ*NI  [b][j][i]
    float* spart = delta + (size_t)BB * NJ * NI;            // NCHUNK*BB*NJ*DJ

    dim3 blk(256);
    // 6 launches: A0 -> BV0 -> A1(softmax fused) -> BV1 -> A2(fused) -> V
    k_A0<<<GRID_MAIN, blk, 0, stream>>>(u, W, spart);
    k_BV<<<GRID_MAIN, blk, 0, stream>>>(u, W, spart, delta, 0);
    k_Af<<<GRID_MAIN, blk, 0, stream>>>(u, W, delta, spart);
    k_BV<<<GRID_MAIN, blk, 0, stream>>>(u, W, spart, delta, 1);
    k_Af<<<GRID_MAIN, blk, 0, stream>>>(u, W, delta, spart);
    k_V<<<GRID_MAIN, blk, 0, stream>>>(spart, out);
}

// Round 10
// 119.498 us; speedup vs baseline: 1.4556x; 1.3545x over previous
//
#include <hip/hip_runtime.h>
#include <math.h>

// Problem constants (CapsNet routing)
#define BB   256   // batch
#define NI   1152  // input capsules
#define DI   8     // input dim
#define NJ   10    // output capsules
#define DJ   16    // output dim
#define NCHUNK 18  // NI / CHUNK
#define CHUNK  64  // i per block
#define BG     32  // batch per block
#define NBG    8   // BB / BG
#define GRID_MAIN (NJ * NCHUNK * NBG)   // 1440 = 8 XCD x 180

typedef _Float16 half2_t __attribute__((ext_vector_type(2)));
typedef _Float16 half4_t __attribute__((ext_vector_type(4)));
typedef _Float16 half8_t __attribute__((ext_vector_type(8)));

// DPP cross-lane adds (VALU pipe, no LDS traffic)
// 0x124 row_ror:4, 0x128 row_ror:8 (16-lane row); 0x0B1 quad lane^1, 0x04E quad lane^2
template <int CTRL>
__device__ __forceinline__ float dpp_add(float x) {
    int xi = __float_as_int(x);
    int yi = __builtin_amdgcn_update_dpp(0, xi, CTRL, 0xF, 0xF, true);
    return x + __int_as_float(yi);
}

// f16 dot-8 with f32 accumulation: 4 chained v_dot2_f32_f16
__device__ __forceinline__ float dot16(half8_t w, half8_t uu) {
    half2_t w0 = {w[0], w[1]}, w1 = {w[2], w[3]}, w2 = {w[4], w[5]}, w3 = {w[6], w[7]};
    half2_t a0 = {uu[0], uu[1]}, a1 = {uu[2], uu[3]}, a2 = {uu[4], uu[5]}, a3 = {uu[6], uu[7]};
    float acc = __builtin_amdgcn_fdot2(w0, a0, 0.f, false);
    acc = __builtin_amdgcn_fdot2(w1, a1, acc, false);
    acc = __builtin_amdgcn_fdot2(w2, a2, acc, false);
    acc = __builtin_amdgcn_fdot2(w3, a3, acc, false);
    return acc;
}

struct Ctx {
    int j, chunk, bg, i0, b0, tid, il, dq, lane, w, g, xcd, local;
};

// XCD-bijective swizzle: xcd = bid&7 owns local 0..179 -> bg == xcd, all (j,chunk).
// Per-XCD working set: u16 slice 0.6 MB + W16 3.0 MB -> fits the 4 MB L2.
__device__ __forceinline__ Ctx make_ctx(int bid, int tid) {
    Ctx c;
    c.xcd = bid & 7; c.local = bid >> 3;
    int gx = c.xcd * (GRID_MAIN / 8) + c.local;
    c.j = gx % NJ; int r = gx / NJ;
    c.chunk = r % NCHUNK; c.bg = r / NCHUNK;   // bg == xcd by construction
    c.i0 = c.chunk * CHUNK; c.b0 = c.bg * BG;
    c.tid = tid; c.il = tid >> 2; c.dq = tid & 3;
    c.lane = tid & 63; c.w = tid >> 6; c.g = (c.lane >> 4) & 3;
    return c;
}

// W16[j, i0+il, dq*4+q, 0..7] : 4 x half8 (16 VGPR), 64 B contiguous per lane
__device__ __forceinline__ void loadW16(const _Float16* __restrict__ W16, const Ctx& cx,
                                        half8_t* Wh) {
    const half8_t* wp = (const half8_t*)(W16 +
        (((size_t)cx.j * NI + cx.i0 + cx.il) * DJ + cx.dq * 4) * DI);
#pragma unroll
    for (int q = 0; q < 4; ++q) Wh[q] = wp[q];
}

// ---- f32 -> f16 conversion of u and W (runs once per call) ----
__global__ __launch_bounds__(256) void k_cvt(const float* __restrict__ uf,
                                             const float* __restrict__ Wf,
                                             _Float16* __restrict__ u16,
                                             _Float16* __restrict__ W16) {
    int idx = blockIdx.x * 256 + threadIdx.x;
    const int nu4 = (BB * NI * DI) / 4;        // 589824
    const int nw4 = (NJ * NI * DJ * DI) / 4;   // 368640
    if (idx < nu4) {
        float4 v = ((const float4*)uf)[idx];
        half4_t h = {(_Float16)v.x, (_Float16)v.y, (_Float16)v.z, (_Float16)v.w};
        ((half4_t*)u16)[idx] = h;
    } else if (idx < nu4 + nw4) {
        int k = idx - nu4;
        float4 v = ((const float4*)Wf)[k];
        half4_t h = {(_Float16)v.x, (_Float16)v.y, (_Float16)v.z, (_Float16)v.w};
        ((half4_t*)W16)[k] = h;
    }
}

// ---- phase A core: spart[ch][b][j][d] = sum_{i in chunk} c*uhat ----
// Group-of-4 register prefetch: 4 half8 u-loads issued before any compute.
template <int CSRC>
__device__ __forceinline__ void phaseA_body(const Ctx& cx, const _Float16* __restrict__ u16,
                                            const float* __restrict__ ctile,
                                            float* __restrict__ spart,
                                            const half8_t* Wh, float* sres) {
    for (int half = 0; half < 2; ++half) {
        int bbase = cx.b0 + half * 16;
#pragma unroll
        for (int grp = 0; grp < 4; ++grp) {
            half8_t pu[4]; float pc[4];
#pragma unroll
            for (int s2 = 0; s2 < 4; ++s2) {
                int bb = grp * 4 + s2;
                int b = bbase + bb;
                pu[s2] = *(const half8_t*)(u16 + ((size_t)b * NI + cx.i0 + cx.il) * DI);
                pc[s2] = (CSRC == 1) ? ctile[(half * 16 + bb) * CHUNK + cx.il]
                                     : 0.1f;   // softmax of zeros over NJ=10
            }
#pragma unroll
            for (int s2 = 0; s2 < 4; ++s2) {
                float p[4];
#pragma unroll
                for (int q = 0; q < 4; ++q) p[q] = pc[s2] * dot16(Wh[q], pu[s2]);
#pragma unroll
                for (int q = 0; q < 4; ++q) p[q] = dpp_add<0x124>(p[q]);
#pragma unroll
                for (int q = 0; q < 4; ++q) p[q] = dpp_add<0x128>(p[q]);
                if ((cx.lane & 12) == 0) {
                    float4 v4; v4.x = p[0]; v4.y = p[1]; v4.z = p[2]; v4.w = p[3];
                    *(float4*)&sres[(((grp * 4 + s2) * 17) + (cx.w * 4 + cx.g)) * 16 + cx.dq * 4] = v4;
                }
            }
        }
        __syncthreads();
        {
            int bb16 = cx.tid >> 4, dd = cx.tid & 15;
            float s2 = 0.f;
#pragma unroll
            for (int gg = 0; gg < 16; ++gg) s2 += sres[((bb16 * 17) + gg) * 16 + dd];
            spart[(((size_t)cx.chunk * BB + bbase + bb16) * NJ + cx.j) * DJ + dd] = s2;
        }
        __syncthreads();
    }
}

// ---- k_A0: iteration 0 (c = 0.1 analytic) ----
__global__ __launch_bounds__(256) void k_A0(const _Float16* __restrict__ u16,
                                            const _Float16* __restrict__ W16,
                                            float* __restrict__ spart) {
    __shared__ __align__(16) float sres[16 * 17 * 16];   // 17408 B
    Ctx cx = make_ctx(blockIdx.x, threadIdx.x);
    half8_t Wh[4];
    loadW16(W16, cx, Wh);
    phaseA_body<0>(cx, u16, nullptr, spart, Wh, sres);
}

// ---- k_Af: softmax fused (f32 prologue from delta), then f16 phase A ----
__global__ __launch_bounds__(256) void k_Af(const _Float16* __restrict__ u16,
                                            const _Float16* __restrict__ W16,
                                            const float* __restrict__ delta,
                                            float* __restrict__ spart) {
    __shared__ __align__(16) float sres[16 * 17 * 16];   // 17408 B
    __shared__ __align__(16) float ctile[BG * CHUNK];    // 8192 B
    Ctx cx = make_ctx(blockIdx.x, threadIdx.x);
    half8_t Wh[4];
    loadW16(W16, cx, Wh);

    // softmax prologue: 2048 (b',i') pairs, 8 per thread, coalesced over i'
#pragma unroll
    for (int p = 0; p < 8; ++p) {
        int idx = p * 256 + cx.tid;        // 0..2047
        int bb = idx >> 6;                 // 0..31
        int ii = idx & 63;                 // 0..63
        int b = cx.b0 + bb;
        const float* dp = delta + (size_t)b * NJ * NI + cx.i0 + ii;
        float x[NJ];
        float mx = -1e30f;
#pragma unroll
        for (int jj = 0; jj < NJ; ++jj) {
            x[jj] = dp[(size_t)jj * NI];
            mx = fmaxf(mx, x[jj]);
        }
        float ssum = 0.f;
#pragma unroll
        for (int jj = 0; jj < NJ; ++jj) { x[jj] = __expf(x[jj] - mx); ssum += x[jj]; }
        ctile[bb * CHUNK + ii] = x[cx.j] / ssum;
    }
    __syncthreads();

    phaseA_body<1>(cx, u16, ctile, spart, Wh, sres);
}

// ---- k_BV: v = squash(sum_ch spart) in LDS, then delta (+)= v . uhat ----
__global__ __launch_bounds__(256) void k_BV(const _Float16* __restrict__ u16,
                                            const _Float16* __restrict__ W16,
                                            const float* __restrict__ spart,
                                            float* __restrict__ delta, int accum) {
    __shared__ __align__(16) float vsm[BG * DJ];       // 2 KB
    __shared__ __align__(16) float bres[BG * CHUNK];   // 8 KB
    Ctx cx = make_ctx(blockIdx.x, threadIdx.x);
    half8_t Wh[4];
    loadW16(W16, cx, Wh);

    {
        int bb2 = cx.tid >> 4, dd = cx.tid & 15;
#pragma unroll
        for (int h = 0; h < 2; ++h) {
            int bb = bb2 + 16 * h;
            int b = cx.b0 + bb;
            float s = 0.f;
#pragma unroll
            for (int ch = 0; ch < NCHUNK; ++ch)
                s += spart[(((size_t)ch * BB + b) * NJ + cx.j) * DJ + dd];
            float sq = s * s;
            sq = dpp_add<0x0B1>(sq);
            sq = dpp_add<0x04E>(sq);
            sq = dpp_add<0x124>(sq);
            sq = dpp_add<0x128>(sq);
            float scale = (sq / (1.f + sq)) / sqrtf(sq + 1e-7f);
            vsm[bb * DJ + dd] = s * scale;
        }
    }
    __syncthreads();

#pragma unroll
    for (int grp = 0; grp < 8; ++grp) {
        half8_t pu[4];
#pragma unroll
        for (int s2 = 0; s2 < 4; ++s2) {
            int b = cx.b0 + grp * 4 + s2;
            pu[s2] = *(const half8_t*)(u16 + ((size_t)b * NI + cx.i0 + cx.il) * DI);
        }
#pragma unroll
        for (int s2 = 0; s2 < 4; ++s2) {
            int bb = grp * 4 + s2;
            float4 vv = *(const float4*)&vsm[bb * DJ + cx.dq * 4];
            float p = vv.x * dot16(Wh[0], pu[s2]);
            p = fmaf(vv.y, dot16(Wh[1], pu[s2]), p);
            p = fmaf(vv.z, dot16(Wh[2], pu[s2]), p);
            p = fmaf(vv.w, dot16(Wh[3], pu[s2]), p);
            p = dpp_add<0x0B1>(p);   // lane^1
            p = dpp_add<0x04E>(p);   // lane^2
            if (cx.dq == 0) bres[bb * CHUNK + cx.il] = p;
        }
    }

    __syncthreads();
#pragma unroll
    for (int h = 0; h < 2; ++h) {
        int bb = (cx.tid >> 4) + 16 * h;
        int q  = cx.tid & 15;
        float4 val = ((const float4*)(bres + bb * CHUNK))[q];
        float* dst = delta + (((size_t)(cx.b0 + bb) * NJ + cx.j) * NI + cx.i0) + q * 4;
        if (accum) {
            float4 old = *(const float4*)dst;
            val.x += old.x; val.y += old.y; val.z += old.z; val.w += old.w;
        }
        *(float4*)dst = val;
    }
}

// ---- k_V: out = squash(sum_ch spart), XCD-local indexing ----
__global__ __launch_bounds__(256) void k_V(const float* __restrict__ spart,
                                           float* __restrict__ out) {
    Ctx cx = make_ctx(blockIdx.x, threadIdx.x);
    int idx_local = cx.local * 256 + cx.tid;
    if (idx_local < BG * NJ * DJ) {            // 5120 items per XCD
        int gidx = cx.xcd * (BG * NJ * DJ) + idx_local;   // = (b*NJ+j)*DJ+d
        float s = 0.f;
#pragma unroll
        for (int ch = 0; ch < NCHUNK; ++ch)
            s += spart[(size_t)ch * (BB * NJ * DJ) + gidx];
        float sq = s * s;
        sq = dpp_add<0x0B1>(sq);
        sq = dpp_add<0x04E>(sq);
        sq = dpp_add<0x124>(sq);
        sq = dpp_add<0x128>(sq);
        float scale = (sq / (1.f + sq)) / sqrtf(sq + 1e-7f);
        out[gidx] = s * scale;
    }
}

extern "C" void kernel_launch(void* const* d_in, const int* in_sizes, int n_in,
                              void* d_out, int out_size, void* d_ws, size_t ws_size,
                              hipStream_t stream) {
    const float* u = (const float*)d_in[0];   // (256,1152,8)
    const float* W = (const float*)d_in[1];   // (10,1152,16,8)
    float* out = (float*)d_out;               // (256,10,16)
    float* ws  = (float*)d_ws;

    float*     delta = ws;                                        // BB*NJ*NI f32
    float*     spart = delta + (size_t)BB * NJ * NI;              // NCHUNK*BB*NJ*DJ f32
    _Float16*  u16   = (_Float16*)(spart + (size_t)NCHUNK * BB * NJ * DJ);
    _Float16*  W16   = u16 + (size_t)BB * NI * DI;

    dim3 blk(256);
    const int GRID_CVT = ((BB * NI * DI) / 4 + (NJ * NI * DJ * DI) / 4) / 256;  // 3744

    // convert inputs to f16 (deterministic, every call)
    k_cvt<<<GRID_CVT, blk, 0, stream>>>(u, W, u16, W16);
    // 6 routing launches: A0 -> BV0 -> A1(softmax fused) -> BV1 -> A2(fused) -> V
    k_A0<<<GRID_MAIN, blk, 0, stream>>>(u16, W16, spart);
    k_BV<<<GRID_MAIN, blk, 0, stream>>>(u16, W16, spart, delta, 0);
    k_Af<<<GRID_MAIN, blk, 0, stream>>>(u16, W16, delta, spart);
    k_BV<<<GRID_MAIN, blk, 0, stream>>>(u16, W16, spart, delta, 1);
    k_Af<<<GRID_MAIN, blk, 0, stream>>>(u16, W16, delta, spart);
    k_V<<<GRID_MAIN, blk, 0, stream>>>(spart, out);
}

// Round 11
// 115.859 us; speedup vs baseline: 1.5014x; 1.0314x over previous
//
#include <hip/hip_runtime.h>
#include <math.h>

// Problem constants (CapsNet routing)
#define BB   256   // batch
#define NI   1152  // input capsules
#define DI   8     // input dim
#define NJ   10    // output capsules
#define DJ   16    // output dim
#define NCHUNK 18  // NI / CHUNK
#define CHUNK  64  // i per block
#define BG     32  // batch per block
#define NBG    8   // BB / BG
#define GRID_MAIN (NJ * NCHUNK * NBG)   // 1440 = 8 XCD x 180

typedef _Float16 half2_t __attribute__((ext_vector_type(2)));
typedef _Float16 half4_t __attribute__((ext_vector_type(4)));
typedef _Float16 half8_t __attribute__((ext_vector_type(8)));

// DPP cross-lane adds (VALU pipe, no LDS traffic)
// 0x124 row_ror:4, 0x128 row_ror:8 (16-lane row); 0x0B1 quad lane^1, 0x04E quad lane^2
template <int CTRL>
__device__ __forceinline__ float dpp_add(float x) {
    int xi = __float_as_int(x);
    int yi = __builtin_amdgcn_update_dpp(0, xi, CTRL, 0xF, 0xF, true);
    return x + __int_as_float(yi);
}

// f16 dot-8 with f32 accumulation: 4 chained v_dot2_f32_f16
__device__ __forceinline__ float dot16(half8_t w, half8_t uu) {
    half2_t w0 = {w[0], w[1]}, w1 = {w[2], w[3]}, w2 = {w[4], w[5]}, w3 = {w[6], w[7]};
    half2_t a0 = {uu[0], uu[1]}, a1 = {uu[2], uu[3]}, a2 = {uu[4], uu[5]}, a3 = {uu[6], uu[7]};
    float acc = __builtin_amdgcn_fdot2(w0, a0, 0.f, false);
    acc = __builtin_amdgcn_fdot2(w1, a1, acc, false);
    acc = __builtin_amdgcn_fdot2(w2, a2, acc, false);
    acc = __builtin_amdgcn_fdot2(w3, a3, acc, false);
    return acc;
}

struct Ctx {
    int j, chunk, bg, i0, b0, tid, il, dq, lane, w, g, xcd, local;
};

// XCD-bijective swizzle: xcd = bid&7 owns local 0..179 -> bg == xcd, all (j,chunk).
// Per-XCD working set: u16 slice 0.6 MB + W16 3.0 MB -> fits the 4 MB L2.
__device__ __forceinline__ Ctx make_ctx(int bid, int tid) {
    Ctx c;
    c.xcd = bid & 7; c.local = bid >> 3;
    int gx = c.xcd * (GRID_MAIN / 8) + c.local;
    c.j = gx % NJ; int r = gx / NJ;
    c.chunk = r % NCHUNK; c.bg = r / NCHUNK;   // bg == xcd by construction
    c.i0 = c.chunk * CHUNK; c.b0 = c.bg * BG;
    c.tid = tid; c.il = tid >> 2; c.dq = tid & 3;
    c.lane = tid & 63; c.w = tid >> 6; c.g = (c.lane >> 4) & 3;
    return c;
}

// W16[j, i0+il, dq*4+q, 0..7] : 4 x half8 (16 VGPR), 64 B contiguous per lane
__device__ __forceinline__ void loadW16(const _Float16* __restrict__ W16, const Ctx& cx,
                                        half8_t* Wh) {
    const half8_t* wp = (const half8_t*)(W16 +
        (((size_t)cx.j * NI + cx.i0 + cx.il) * DJ + cx.dq * 4) * DI);
#pragma unroll
    for (int q = 0; q < 4; ++q) Wh[q] = wp[q];
}

// ---- f32 -> f16 conversion of u and W (runs once per call) ----
__global__ __launch_bounds__(256) void k_cvt(const float* __restrict__ uf,
                                             const float* __restrict__ Wf,
                                             _Float16* __restrict__ u16,
                                             _Float16* __restrict__ W16) {
    int idx = blockIdx.x * 256 + threadIdx.x;
    const int nu4 = (BB * NI * DI) / 4;        // 589824
    const int nw4 = (NJ * NI * DJ * DI) / 4;   // 368640
    if (idx < nu4) {
        float4 v = ((const float4*)uf)[idx];
        half4_t h = {(_Float16)v.x, (_Float16)v.y, (_Float16)v.z, (_Float16)v.w};
        ((half4_t*)u16)[idx] = h;
    } else if (idx < nu4 + nw4) {
        int k = idx - nu4;
        float4 v = ((const float4*)Wf)[k];
        half4_t h = {(_Float16)v.x, (_Float16)v.y, (_Float16)v.z, (_Float16)v.w};
        ((half4_t*)W16)[k] = h;
    }
}

// ---- phase A core: spart[ch][b][j][d] = sum_{i in chunk} c*uhat ----
// Double-buffered u prefetch: group g+1's 4 half8 loads issue BEFORE group g's
// compute, so the only VMEM stall is the prologue. ci read at compute time
// (LDS/immediate, cheap).
template <int CSRC>
__device__ __forceinline__ void phaseA_body(const Ctx& cx, const _Float16* __restrict__ u16,
                                            const float* __restrict__ ctile,
                                            float* __restrict__ spart,
                                            const half8_t* Wh, float* sres) {
    for (int half = 0; half < 2; ++half) {
        int bbase = cx.b0 + half * 16;
        half8_t puA[4];
#pragma unroll
        for (int s2 = 0; s2 < 4; ++s2) {
            int b = bbase + s2;
            puA[s2] = *(const half8_t*)(u16 + ((size_t)b * NI + cx.i0 + cx.il) * DI);
        }
#pragma unroll
        for (int grp = 0; grp < 4; ++grp) {
            half8_t puB[4];
            if (grp < 3) {
#pragma unroll
                for (int s2 = 0; s2 < 4; ++s2) {
                    int b = bbase + (grp + 1) * 4 + s2;
                    puB[s2] = *(const half8_t*)(u16 + ((size_t)b * NI + cx.i0 + cx.il) * DI);
                }
            }
#pragma unroll
            for (int s2 = 0; s2 < 4; ++s2) {
                int bb = grp * 4 + s2;
                float ci = (CSRC == 1) ? ctile[(half * 16 + bb) * CHUNK + cx.il]
                                       : 0.1f;   // softmax of zeros over NJ=10
                float p[4];
#pragma unroll
                for (int q = 0; q < 4; ++q) p[q] = ci * dot16(Wh[q], puA[s2]);
#pragma unroll
                for (int q = 0; q < 4; ++q) p[q] = dpp_add<0x124>(p[q]);
#pragma unroll
                for (int q = 0; q < 4; ++q) p[q] = dpp_add<0x128>(p[q]);
                if ((cx.lane & 12) == 0) {
                    float4 v4; v4.x = p[0]; v4.y = p[1]; v4.z = p[2]; v4.w = p[3];
                    *(float4*)&sres[((bb * 17) + (cx.w * 4 + cx.g)) * 16 + cx.dq * 4] = v4;
                }
            }
            if (grp < 3) {
#pragma unroll
                for (int s2 = 0; s2 < 4; ++s2) puA[s2] = puB[s2];
            }
        }
        __syncthreads();
        {
            int bb16 = cx.tid >> 4, dd = cx.tid & 15;
            float s2 = 0.f;
#pragma unroll
            for (int gg = 0; gg < 16; ++gg) s2 += sres[((bb16 * 17) + gg) * 16 + dd];
            spart[(((size_t)cx.chunk * BB + bbase + bb16) * NJ + cx.j) * DJ + dd] = s2;
        }
        __syncthreads();
    }
}

// ---- k_A0: iteration 0 (c = 0.1 analytic) ----
__global__ __launch_bounds__(256) void k_A0(const _Float16* __restrict__ u16,
                                            const _Float16* __restrict__ W16,
                                            float* __restrict__ spart) {
    __shared__ __align__(16) float sres[16 * 17 * 16];   // 17408 B
    Ctx cx = make_ctx(blockIdx.x, threadIdx.x);
    half8_t Wh[4];
    loadW16(W16, cx, Wh);
    phaseA_body<0>(cx, u16, nullptr, spart, Wh, sres);
}

// ---- k_Af: softmax fused (reads f16 delta), then f16 phase A ----
__global__ __launch_bounds__(256) void k_Af(const _Float16* __restrict__ u16,
                                            const _Float16* __restrict__ W16,
                                            const _Float16* __restrict__ delta,
                                            float* __restrict__ spart) {
    __shared__ __align__(16) float sres[16 * 17 * 16];   // 17408 B
    __shared__ __align__(16) float ctile[BG * CHUNK];    // 8192 B
    Ctx cx = make_ctx(blockIdx.x, threadIdx.x);
    half8_t Wh[4];
    loadW16(W16, cx, Wh);

    // softmax prologue: 2048 (b',i') pairs, 8 per thread, coalesced over i'
#pragma unroll
    for (int p = 0; p < 8; ++p) {
        int idx = p * 256 + cx.tid;        // 0..2047
        int bb = idx >> 6;                 // 0..31
        int ii = idx & 63;                 // 0..63
        int b = cx.b0 + bb;
        const _Float16* dp = delta + (size_t)b * NJ * NI + cx.i0 + ii;
        float x[NJ];
        float mx = -1e30f;
#pragma unroll
        for (int jj = 0; jj < NJ; ++jj) {
            x[jj] = (float)dp[(size_t)jj * NI];
            mx = fmaxf(mx, x[jj]);
        }
        float ssum = 0.f;
#pragma unroll
        for (int jj = 0; jj < NJ; ++jj) { x[jj] = __expf(x[jj] - mx); ssum += x[jj]; }
        ctile[bb * CHUNK + ii] = x[cx.j] / ssum;
    }
    __syncthreads();

    phaseA_body<1>(cx, u16, ctile, spart, Wh, sres);
}

// ---- k_BV: v = squash(sum_ch spart) in LDS, then delta16 (+)= v . uhat ----
__global__ __launch_bounds__(256) void k_BV(const _Float16* __restrict__ u16,
                                            const _Float16* __restrict__ W16,
                                            const float* __restrict__ spart,
                                            _Float16* __restrict__ delta, int accum) {
    __shared__ __align__(16) float vsm[BG * DJ];       // 2 KB
    __shared__ __align__(16) float bres[BG * CHUNK];   // 8 KB
    Ctx cx = make_ctx(blockIdx.x, threadIdx.x);
    half8_t Wh[4];
    loadW16(W16, cx, Wh);

    // prefetch grp0 u BEFORE the squash prologue (prologue covers the latency)
    half8_t puA[4];
#pragma unroll
    for (int s2 = 0; s2 < 4; ++s2) {
        int b = cx.b0 + s2;
        puA[s2] = *(const half8_t*)(u16 + ((size_t)b * NI + cx.i0 + cx.il) * DI);
    }

    {
        int bb2 = cx.tid >> 4, dd = cx.tid & 15;
#pragma unroll
        for (int h = 0; h < 2; ++h) {
            int bb = bb2 + 16 * h;
            int b = cx.b0 + bb;
            float s = 0.f;
#pragma unroll
            for (int ch = 0; ch < NCHUNK; ++ch)
                s += spart[(((size_t)ch * BB + b) * NJ + cx.j) * DJ + dd];
            float sq = s * s;
            sq = dpp_add<0x0B1>(sq);
            sq = dpp_add<0x04E>(sq);
            sq = dpp_add<0x124>(sq);
            sq = dpp_add<0x128>(sq);
            float scale = (sq / (1.f + sq)) / sqrtf(sq + 1e-7f);
            vsm[bb * DJ + dd] = s * scale;
        }
    }
    __syncthreads();

#pragma unroll
    for (int grp = 0; grp < 8; ++grp) {
        half8_t puB[4];
        if (grp < 7) {
#pragma unroll
            for (int s2 = 0; s2 < 4; ++s2) {
                int b = cx.b0 + (grp + 1) * 4 + s2;
                puB[s2] = *(const half8_t*)(u16 + ((size_t)b * NI + cx.i0 + cx.il) * DI);
            }
        }
#pragma unroll
        for (int s2 = 0; s2 < 4; ++s2) {
            int bb = grp * 4 + s2;
            float4 vv = *(const float4*)&vsm[bb * DJ + cx.dq * 4];
            float p = vv.x * dot16(Wh[0], puA[s2]);
            p = fmaf(vv.y, dot16(Wh[1], puA[s2]), p);
            p = fmaf(vv.z, dot16(Wh[2], puA[s2]), p);
            p = fmaf(vv.w, dot16(Wh[3], puA[s2]), p);
            p = dpp_add<0x0B1>(p);   // lane^1
            p = dpp_add<0x04E>(p);   // lane^2
            if (cx.dq == 0) bres[bb * CHUNK + cx.il] = p;
        }
        if (grp < 7) {
#pragma unroll
            for (int s2 = 0; s2 < 4; ++s2) puA[s2] = puB[s2];
        }
    }

    __syncthreads();
    // epilogue: 4 halves per thread (8B), coalesced 128B per bb-row; f32 accum
#pragma unroll
    for (int h = 0; h < 2; ++h) {
        int bb = (cx.tid >> 4) + 16 * h;
        int q  = cx.tid & 15;
        float4 val = ((const float4*)(bres + bb * CHUNK))[q];
        _Float16* dst = delta + (((size_t)(cx.b0 + bb) * NJ + cx.j) * NI + cx.i0) + q * 4;
        half4_t o;
        if (accum) {
            half4_t old = *(const half4_t*)dst;
            o[0] = (_Float16)(val.x + (float)old[0]);
            o[1] = (_Float16)(val.y + (float)old[1]);
            o[2] = (_Float16)(val.z + (float)old[2]);
            o[3] = (_Float16)(val.w + (float)old[3]);
        } else {
            o[0] = (_Float16)val.x; o[1] = (_Float16)val.y;
            o[2] = (_Float16)val.z; o[3] = (_Float16)val.w;
        }
        *(half4_t*)dst = o;
    }
}

// ---- k_V: out = squash(sum_ch spart), 160 blocks (20 per XCD) ----
__global__ __launch_bounds__(256) void k_V(const float* __restrict__ spart,
                                           float* __restrict__ out) {
    int xcd = blockIdx.x & 7, local = blockIdx.x >> 3;
    int idx_local = local * 256 + threadIdx.x;          // 0..5119
    int gidx = xcd * (BG * NJ * DJ) + idx_local;        // = (b*NJ+j)*DJ+d
    float s = 0.f;
#pragma unroll
    for (int ch = 0; ch < NCHUNK; ++ch)
        s += spart[(size_t)ch * (BB * NJ * DJ) + gidx];
    float sq = s * s;
    sq = dpp_add<0x0B1>(sq);
    sq = dpp_add<0x04E>(sq);
    sq = dpp_add<0x124>(sq);
    sq = dpp_add<0x128>(sq);
    float scale = (sq / (1.f + sq)) / sqrtf(sq + 1e-7f);
    out[gidx] = s * scale;
}

extern "C" void kernel_launch(void* const* d_in, const int* in_sizes, int n_in,
                              void* d_out, int out_size, void* d_ws, size_t ws_size,
                              hipStream_t stream) {
    const float* u = (const float*)d_in[0];   // (256,1152,8)
    const float* W = (const float*)d_in[1];   // (10,1152,16,8)
    float* out = (float*)d_out;               // (256,10,16)

    float*     spart = (float*)d_ws;                              // NCHUNK*BB*NJ*DJ f32
    _Float16*  delta = (_Float16*)(spart + (size_t)NCHUNK * BB * NJ * DJ);  // BB*NJ*NI f16
    _Float16*  u16   = delta + (size_t)BB * NJ * NI;
    _Float16*  W16   = u16 + (size_t)BB * NI * DI;

    dim3 blk(256);
    const int GRID_CVT = ((BB * NI * DI) / 4 + (NJ * NI * DJ * DI) / 4) / 256;  // 3744

    // convert inputs to f16 (deterministic, every call)
    k_cvt<<<GRID_CVT, blk, 0, stream>>>(u, W, u16, W16);
    // 6 routing launches: A0 -> BV0 -> A1(softmax fused) -> BV1 -> A2(fused) -> V
    k_A0<<<GRID_MAIN, blk, 0, stream>>>(u16, W16, spart);
    k_BV<<<GRID_MAIN, blk, 0, stream>>>(u16, W16, spart, delta, 0);
    k_Af<<<GRID_MAIN, blk, 0, stream>>>(u16, W16, delta, spart);
    k_BV<<<GRID_MAIN, blk, 0, stream>>>(u16, W16, spart, delta, 1);
    k_Af<<<GRID_MAIN, blk, 0, stream>>>(u16, W16, delta, spart);
    k_V<<<160, blk, 0, stream>>>(spart, out);
}